// Round 1
// baseline (483.199 us; speedup 1.0000x reference)
//
#include <hip/hip_runtime.h>

// HaarWavelet2D fused kernel for MI355X.
// x: (8,64,256,256) fp32, level=2 hardcoded.
// out = [low_freq (33554432 floats), high_freq (33554432 floats)].
//
// Per block: one channel-image (bc in [0,512)) x one 64x64 output tile.
// All intermediates staged in LDS with halos so each output is written once
// and input read ~1.2x (halo overlap).

constexpr int IH = 256, IW = 256;
constexpr int TILE = 64;
constexpr int XT = 70;  // x tile:      origin (i0-3), global rows [i0-3, i0+66]
constexpr int LT = 69;  // ll1 tile:    origin (i0-3), valid global [0,254]
constexpr int CT = 65;  // ch1 tile:    origin (i0-1), valid global [0,254]
constexpr int FT = 68;  // lf1 tile:    origin (i0-2), valid global [0,255]
constexpr int QT = 34;  // ll2/ch2:     origin (i0/2-1), valid global [0,127]

__global__ __launch_bounds__(256)
void haar_fused(const float* __restrict__ x,
                float* __restrict__ out_low,
                float* __restrict__ out_high) {
  const int bc = blockIdx.y;                  // 0..511 (b*64+c)
  const int ti = blockIdx.x >> 2;             // 0..3
  const int tj = blockIdx.x & 3;              // 0..3
  const int i0 = ti * TILE, j0 = tj * TILE;
  const int tid = threadIdx.x;

  __shared__ float sX[XT * XT];     // x tile; reused for lf1 (FT*FT <= XT*XT)
  __shared__ float sLL1[LT * LT];
  __shared__ float sCH1[CT * CT];
  __shared__ float sLL2[QT * QT];
  __shared__ float sCH2[QT * QT];
  // total: (4900+4761+4225+1156+1156)*4 = 64,792 B  (<= 64 KB)

  const float* xc = x + (size_t)bc * (IH * IW);

  // ---- 1. stage x tile (clamped at image borders) ----
  for (int idx = tid; idx < XT * XT; idx += 256) {
    int r = idx / XT, c = idx - r * XT;
    int gr = min(max(i0 - 3 + r, 0), IH - 1);
    int gc = min(max(j0 - 3 + c, 0), IW - 1);
    sX[idx] = xc[gr * IW + gc];
  }
  __syncthreads();

  // ---- 2a. ll1 (69x69, origin i0-3) ----
  for (int idx = tid; idx < LT * LT; idx += 256) {
    int r = idx / LT, c = idx - r * LT;
    float x00 = sX[r * XT + c];
    float x01 = sX[r * XT + c + 1];
    float x10 = sX[(r + 1) * XT + c];
    float x11 = sX[(r + 1) * XT + c + 1];
    sLL1[idx] = 0.25f * (x00 + x01 + x10 + x11);
  }
  // ---- 2b. ch1 = |lh|+|hl|+|hh| (65x65, origin i0-1; x-slot offset +2) ----
  for (int idx = tid; idx < CT * CT; idx += 256) {
    int r = idx / CT, c = idx - r * CT;
    int xr = r + 2, xcol = c + 2;
    float x00 = sX[xr * XT + xcol];
    float x01 = sX[xr * XT + xcol + 1];
    float x10 = sX[(xr + 1) * XT + xcol];
    float x11 = sX[(xr + 1) * XT + xcol + 1];
    float sa = x00 + x01, sb = x10 + x11;
    float da = x00 - x01, db = x10 - x11;
    float lh = 0.25f * (sa - sb);
    float hl = 0.25f * (da + db);
    float hh = 0.25f * (da - db);
    sCH1[idx] = fabsf(lh) + fabsf(hl) + fabsf(hh);
  }
  __syncthreads();

  // ---- 3. lf1 = resize 255->256 of ll1 (68x68, origin i0-2), into sX ----
  // jax linear resize: sample = (i+0.5)*255/256 - 0.5, clamped to [0,254].
  for (int idx = tid; idx < FT * FT; idx += 256) {
    int r = idx / FT, c = idx - r * FT;
    int R = i0 - 2 + r, C = j0 - 2 + c;
    float cr = (R + 0.5f) * (255.0f / 256.0f) - 0.5f;
    cr = fminf(fmaxf(cr, 0.0f), 254.0f);
    int a0 = (int)cr; if (a0 > 253) a0 = 253;
    float fr = cr - (float)a0;
    float cc = (C + 0.5f) * (255.0f / 256.0f) - 0.5f;
    cc = fminf(fmaxf(cc, 0.0f), 254.0f);
    int b0 = (int)cc; if (b0 > 253) b0 = 253;
    float fc = cc - (float)b0;
    int rs = a0 - (i0 - 3), cs = b0 - (j0 - 3);
    float v00 = sLL1[rs * LT + cs],       v01 = sLL1[rs * LT + cs + 1];
    float v10 = sLL1[(rs + 1) * LT + cs], v11 = sLL1[(rs + 1) * LT + cs + 1];
    float top = v00 + fc * (v01 - v00);
    float bot = v10 + fc * (v11 - v10);
    sX[idx] = top + fr * (bot - top);   // lf1 stored with pitch FT
  }
  __syncthreads();

  // ---- 4. stride-2 Haar on lf1: ll2/ch2 (34x34, origin p0=i0/2-1) ----
  for (int idx = tid; idx < QT * QT; idx += 256) {
    int pr = idx / QT, pc = idx - pr * QT;
    float f00 = sX[(2 * pr) * FT + 2 * pc];
    float f01 = sX[(2 * pr) * FT + 2 * pc + 1];
    float f10 = sX[(2 * pr + 1) * FT + 2 * pc];
    float f11 = sX[(2 * pr + 1) * FT + 2 * pc + 1];
    float sa = f00 + f01, sb = f10 + f11;
    float da = f00 - f01, db = f10 - f11;
    sLL2[idx] = 0.25f * (sa + sb);
    float lh = 0.25f * (sa - sb);
    float hl = 0.25f * (da + db);
    float hh = 0.25f * (da - db);
    sCH2[idx] = fabsf(lh) + fabsf(hl) + fabsf(hh);
  }
  __syncthreads();

  // ---- 5. outputs: low = R128(ll2); high = 0.5*(R255(ch1) + R128(ll2-side ch2)) ----
  const int p0 = (i0 >> 1) - 1, q0 = (j0 >> 1) - 1;
  const size_t obase = (size_t)bc * (IH * IW);
  for (int idx = tid; idx < TILE * TILE; idx += 256) {
    int r = idx >> 6, c = idx & 63;
    int i = i0 + r, j = j0 + c;

    // R255 weights (ch1)
    float cr1 = (i + 0.5f) * (255.0f / 256.0f) - 0.5f;
    cr1 = fminf(fmaxf(cr1, 0.0f), 254.0f);
    int a0 = (int)cr1; if (a0 > 253) a0 = 253;
    float fr1 = cr1 - (float)a0;
    float cc1 = (j + 0.5f) * (255.0f / 256.0f) - 0.5f;
    cc1 = fminf(fmaxf(cc1, 0.0f), 254.0f);
    int b0 = (int)cc1; if (b0 > 253) b0 = 253;
    float fc1 = cc1 - (float)b0;
    int rs = a0 - (i0 - 1), cs = b0 - (j0 - 1);
    float h00 = sCH1[rs * CT + cs],       h01 = sCH1[rs * CT + cs + 1];
    float h10 = sCH1[(rs + 1) * CT + cs], h11 = sCH1[(rs + 1) * CT + cs + 1];
    float ht = h00 + fc1 * (h01 - h00);
    float hb = h10 + fc1 * (h11 - h10);
    float hi1 = ht + fr1 * (hb - ht);

    // R128 weights (ll2 / ch2): sample = 0.5*i - 0.25, clamp [0,127]
    float cr2 = 0.5f * (float)i - 0.25f;
    cr2 = fminf(fmaxf(cr2, 0.0f), 127.0f);
    int p = (int)cr2; if (p > 126) p = 126;
    float fr2 = cr2 - (float)p;
    float cc2 = 0.5f * (float)j - 0.25f;
    cc2 = fminf(fmaxf(cc2, 0.0f), 127.0f);
    int q = (int)cc2; if (q > 126) q = 126;
    float fc2 = cc2 - (float)q;
    int ps = p - p0, qs = q - q0;

    float g00 = sCH2[ps * QT + qs],       g01 = sCH2[ps * QT + qs + 1];
    float g10 = sCH2[(ps + 1) * QT + qs], g11 = sCH2[(ps + 1) * QT + qs + 1];
    float gt = g00 + fc2 * (g01 - g00);
    float gb = g10 + fc2 * (g11 - g10);
    float hi2 = gt + fr2 * (gb - gt);

    float l00 = sLL2[ps * QT + qs],       l01 = sLL2[ps * QT + qs + 1];
    float l10 = sLL2[(ps + 1) * QT + qs], l11 = sLL2[(ps + 1) * QT + qs + 1];
    float lt = l00 + fc2 * (l01 - l00);
    float lb = l10 + fc2 * (l11 - l10);
    float lo = lt + fr2 * (lb - lt);

    out_low[obase + (size_t)i * IW + j] = lo;
    out_high[obase + (size_t)i * IW + j] = 0.5f * (hi1 + hi2);
  }
}

extern "C" void kernel_launch(void* const* d_in, const int* in_sizes, int n_in,
                              void* d_out, int out_size, void* d_ws, size_t ws_size,
                              hipStream_t stream) {
  (void)in_sizes; (void)n_in; (void)d_ws; (void)ws_size; (void)out_size;
  const float* x = (const float*)d_in[0];
  // d_in[1] is `level` (==2), hardcoded in the kernel.
  float* out_low = (float*)d_out;
  float* out_high = out_low + (size_t)8 * 64 * 256 * 256;

  dim3 grid(16, 512, 1);   // 16 tiles (4x4) x 512 channel-images
  dim3 block(256, 1, 1);
  haar_fused<<<grid, block, 0, stream>>>(x, out_low, out_high);
}

// Round 3
// 442.218 us; speedup vs baseline: 1.0927x; 1.0927x over previous
//
#include <hip/hip_runtime.h>

// HaarWavelet2D fused, restructured: lane-based indexing, register row-scans,
// hoisted resize weights, float4 staging + stores.
// x: (8,64,256,256) fp32, level=2. out = [low (2^25 floats), high (2^25)].

constexpr int IW = 256, IH = 256;

__device__ __forceinline__ float lerpf(float a, float b, float t) {
  return a + t * (b - a);
}

__global__ __launch_bounds__(256)
void haar_fused(const float* __restrict__ x,
                float* __restrict__ out_low,
                float* __restrict__ out_high) {
  const int bc = blockIdx.y;                 // channel-image 0..511
  const int ti = blockIdx.x >> 2;            // tile row 0..3
  const int tj = blockIdx.x & 3;             // tile col 0..3
  const int i0 = ti * 64, j0 = tj * 64;
  const int tid = threadIdx.x;
  const int lane = tid & 63;
  const int wid = tid >> 6;
  const float c512 = 1.0f / 512.0f;

  // Frames: sX rows ~ global i0-3+xr (70), cols ~ j0-4+xc (72, pitch 72)
  //         sLL1 (69x69) origin (i0-3, j0-3)
  //         sCH1 (65x65) origin (i0-1, j0-1)
  //         lf1 in sX (68x68 pitch 68) origin (i0-2, j0-2)
  //         sLL2/sCH2 (34x34) origin (i0/2-1, j0/2-1)
  __shared__ float sX[70 * 72];     // 5040
  __shared__ float sLL1[69 * 69];   // 4761
  __shared__ float sCH1[65 * 65];   // 4225
  __shared__ float sLL2[34 * 34];   // 1156
  __shared__ float sCH2[34 * 34];   // 1156   total 65,352 B

  const float* xc = x + (size_t)bc * (IH * IW);

  // ---------------- Stage 1: stage x, float4 path for ALL tiles ----------------
  const int colbase = min(max(j0 - 4, 0), IW - 72);  // 0,60,124,184
  const int soff = colbase - j0 + 4;                 // +4 (tj=0), -4 (tj=3), else 0
  for (int idx = tid; idx < 70 * 18; idx += 256) {
    int r = idx / 18;                 // magic-mul, 5 iters total
    int c4 = idx - r * 18;
    int gslot = 4 * c4 + soff;
    if (gslot >= 0 && gslot <= 68) {
      int gr = min(max(i0 - 3 + r, 0), IH - 1);
      const float4 v = *reinterpret_cast<const float4*>(&xc[gr * IW + colbase + 4 * c4]);
      *reinterpret_cast<float4*>(&sX[r * 72 + gslot]) = v;
    }
  }
  if (soff != 0) {                    // block-uniform branch
    __syncthreads();
    if (tid < 70) {
      if (soff > 0) {
        float v = sX[tid * 72 + 4];
        sX[tid * 72 + 0] = v; sX[tid * 72 + 1] = v;
        sX[tid * 72 + 2] = v; sX[tid * 72 + 3] = v;
      } else {
        float v = sX[tid * 72 + 67];
        sX[tid * 72 + 68] = v; sX[tid * 72 + 69] = v;
        sX[tid * 72 + 70] = v; sX[tid * 72 + 71] = v;
      }
    }
  }
  __syncthreads();

  // ------------- Stage 2: ll1 (69x69) + ch1 (65x65), register row-scan -------------
  {
    int r0 = wid * 18;
    int r1 = min(r0 + 18, 69);
    int xc0 = lane + 1;
    float a = sX[r0 * 72 + xc0], b = sX[r0 * 72 + xc0 + 1];
    float s = a + b, d = a - b;
    for (int xr = r0; xr < r1; ++xr) {
      float a2 = sX[(xr + 1) * 72 + xc0], b2 = sX[(xr + 1) * 72 + xc0 + 1];
      float s2 = a2 + b2, d2 = a2 - b2;
      sLL1[xr * 69 + lane] = 0.25f * (s + s2);
      float lh = 0.25f * (s - s2);
      float hl = 0.25f * (d + d2);
      float hh = 0.25f * (d - d2);
      float ch = fabsf(lh) + fabsf(hl) + fabsf(hh);
      if (lane >= 2 && (unsigned)(xr - 2) <= 64u)
        sCH1[(xr - 2) * 65 + (lane - 2)] = ch;
      s = s2; d = d2;
    }
  }
  // fringe: x col pairs xc0=65..69 -> ll1 cols 64..68, ch1 cols 62..64
  for (int f = tid; f < 5 * 69; f += 256) {
    int q = f / 69;
    int xr = f - q * 69;
    int xc0 = 65 + q;
    float a = sX[xr * 72 + xc0], b = sX[xr * 72 + xc0 + 1];
    float a2 = sX[(xr + 1) * 72 + xc0], b2 = sX[(xr + 1) * 72 + xc0 + 1];
    float s = a + b, d = a - b, s2 = a2 + b2, d2 = a2 - b2;
    sLL1[xr * 69 + (xc0 - 1)] = 0.25f * (s + s2);
    if (xc0 <= 67 && (unsigned)(xr - 2) <= 64u) {
      float lh = 0.25f * (s - s2);
      float hl = 0.25f * (d + d2);
      float hh = 0.25f * (d - d2);
      sCH1[(xr - 2) * 65 + (xc0 - 3)] = fabsf(lh) + fabsf(hl) + fabsf(hh);
    }
  }
  __syncthreads();

  // ------------- Stage 3: lf1 = R255(ll1), 68x68 into sX pitch 68 -------------
  {
    int fcc = lane;
    int C = j0 - 2 + fcc;
    float ccf = (float)C - (float)(2 * C + 1) * c512;
    float fc = fminf(fmaxf(ccf, 0.0f), 254.0f) - (float)(C - 1);
    int r0 = wid * 17, r1 = r0 + 17;
    float A = sLL1[r0 * 69 + fcc], B = sLL1[r0 * 69 + fcc + 1];
    float hz = A + fc * (B - A);
    for (int fr = r0; fr < r1; ++fr) {
      float A2 = sLL1[(fr + 1) * 69 + fcc], B2 = sLL1[(fr + 1) * 69 + fcc + 1];
      float hz2 = A2 + fc * (B2 - A2);
      int R = i0 - 2 + fr;
      float crf = (float)R - (float)(2 * R + 1) * c512;
      float fw = fminf(fmaxf(crf, 0.0f), 254.0f) - (float)(R - 1);
      sX[fr * 68 + fcc] = hz + fw * (hz2 - hz);
      hz = hz2;
    }
  }
  // fringe cols 64..67
  for (int f = tid; f < 4 * 68; f += 256) {
    int q = f / 68;
    int fr = f - q * 68;
    int fcc = 64 + q;
    int C = j0 - 2 + fcc;
    float ccf = (float)C - (float)(2 * C + 1) * c512;
    float fc = fminf(fmaxf(ccf, 0.0f), 254.0f) - (float)(C - 1);
    float A = sLL1[fr * 69 + fcc], B = sLL1[fr * 69 + fcc + 1];
    float A2 = sLL1[(fr + 1) * 69 + fcc], B2 = sLL1[(fr + 1) * 69 + fcc + 1];
    int R = i0 - 2 + fr;
    float crf = (float)R - (float)(2 * R + 1) * c512;
    float fw = fminf(fmaxf(crf, 0.0f), 254.0f) - (float)(R - 1);
    float hz = A + fc * (B - A);
    float hz2 = A2 + fc * (B2 - A2);
    sX[fr * 68 + fcc] = hz + fw * (hz2 - hz);
  }
  __syncthreads();

  // ------------- Stage 4: stride-2 Haar on lf1 -> ll2/ch2 (34x34) -------------
  for (int idx = tid; idx < 34 * 32; idx += 256) {
    int pr = idx >> 5, pc = idx & 31;
    int base = (2 * pr) * 68 + 2 * pc;
    float f00 = sX[base], f01 = sX[base + 1];
    float f10 = sX[base + 68], f11 = sX[base + 69];
    float sa = f00 + f01, sb = f10 + f11;
    float da = f00 - f01, db = f10 - f11;
    sLL2[pr * 34 + pc] = 0.25f * (sa + sb);
    sCH2[pr * 34 + pc] =
        fabsf(0.25f * (sa - sb)) + fabsf(0.25f * (da + db)) + fabsf(0.25f * (da - db));
  }
  if (tid < 68) {
    int pr = tid >> 1, pc = 32 + (tid & 1);
    int base = (2 * pr) * 68 + 2 * pc;
    float f00 = sX[base], f01 = sX[base + 1];
    float f10 = sX[base + 68], f11 = sX[base + 69];
    float sa = f00 + f01, sb = f10 + f11;
    float da = f00 - f01, db = f10 - f11;
    sLL2[pr * 34 + pc] = 0.25f * (sa + sb);
    sCH2[pr * 34 + pc] =
        fabsf(0.25f * (sa - sb)) + fabsf(0.25f * (da + db)) + fabsf(0.25f * (da - db));
  }
  __syncthreads();

  // ------------- Stage 5: outputs, 4 consecutive cols/thread, float4 stores -------------
  {
    const int cg = tid & 15, rb = tid >> 4;
    const int cbase = 4 * cg;
    const int q0 = (j0 >> 1) - 1;
    const int p0 = (i0 >> 1) - 1;
    float fc1[4], fc2[4];
#pragma unroll
    for (int m = 0; m < 4; ++m) {
      int jj = j0 + cbase + m;
      float ccf = (float)jj - (float)(2 * jj + 1) * c512;
      fc1[m] = fminf(fmaxf(ccf, 0.0f), 254.0f) - (float)(jj - 1);
      int qu = (jj - 1) >> 1;
      fc2[m] = fminf(fmaxf(0.5f * (float)jj - 0.25f, 0.0f), 127.0f) - (float)qu;
    }
    const int qs0 = ((j0 + cbase - 1) >> 1) - q0;
    const size_t obase = (size_t)bc * (IH * IW);

#pragma unroll
    for (int k = 0; k < 4; ++k) {
      int r = rb + 16 * k;
      int i = i0 + r;
      float crf = (float)i - (float)(2 * i + 1) * c512;
      float fr1 = fminf(fmaxf(crf, 0.0f), 254.0f) - (float)(i - 1);
      int pu = (i - 1) >> 1;
      float fr2 = fminf(fmaxf(0.5f * (float)i - 0.25f, 0.0f), 127.0f) - (float)pu;
      int ps = pu - p0;

      const float* chA = &sCH1[r * 65 + cbase];
      const float* chB = chA + 65;
      const float* llA = &sLL2[ps * 34 + qs0];
      const float* llB = llA + 34;
      const float* c2A = &sCH2[ps * 34 + qs0];
      const float* c2B = c2A + 34;

      float av[5], bv[5];
#pragma unroll
      for (int m = 0; m < 5; ++m) { av[m] = chA[m]; bv[m] = chB[m]; }
      float lav[4], lbv[4], gav[4], gbv[4];
#pragma unroll
      for (int m = 0; m < 4; ++m) {
        lav[m] = llA[m]; lbv[m] = llB[m];
        gav[m] = c2A[m]; gbv[m] = c2B[m];
      }

      float lo[4], hi[4];
#pragma unroll
      for (int m = 0; m < 4; ++m) {
        const int k2 = (m == 0) ? 0 : (m == 3 ? 2 : 1);  // col-slot pattern {0,1,1,2}
        float h1 = lerpf(lerpf(av[m], av[m + 1], fc1[m]),
                         lerpf(bv[m], bv[m + 1], fc1[m]), fr1);
        float l_ = lerpf(lerpf(lav[k2], lav[k2 + 1], fc2[m]),
                         lerpf(lbv[k2], lbv[k2 + 1], fc2[m]), fr2);
        float h2 = lerpf(lerpf(gav[k2], gav[k2 + 1], fc2[m]),
                         lerpf(gbv[k2], gbv[k2 + 1], fc2[m]), fr2);
        lo[m] = l_;
        hi[m] = 0.5f * (h1 + h2);
      }
      float4 lowv = make_float4(lo[0], lo[1], lo[2], lo[3]);
      float4 highv = make_float4(hi[0], hi[1], hi[2], hi[3]);
      size_t off = obase + (size_t)i * IW + (j0 + cbase);
      *reinterpret_cast<float4*>(&out_low[off]) = lowv;
      *reinterpret_cast<float4*>(&out_high[off]) = highv;
    }
  }
}

extern "C" void kernel_launch(void* const* d_in, const int* in_sizes, int n_in,
                              void* d_out, int out_size, void* d_ws, size_t ws_size,
                              hipStream_t stream) {
  (void)in_sizes; (void)n_in; (void)d_ws; (void)ws_size; (void)out_size;
  const float* x = (const float*)d_in[0];
  float* out_low = (float*)d_out;
  float* out_high = out_low + (size_t)8 * 64 * 256 * 256;

  dim3 grid(16, 512, 1);
  dim3 block(256, 1, 1);
  haar_fused<<<grid, block, 0, stream>>>(x, out_low, out_high);
}

// Round 4
// 390.296 us; speedup vs baseline: 1.2380x; 1.1330x over previous
//
#include <hip/hip_runtime.h>

// HaarWavelet2D fused, round 4: 32x64 tiles, no sLL1 (lf1 = direct separable
// 3-tap on x), 3 barriers, 34.6 KB LDS -> 4 blocks/CU (50% occupancy).
// x: (8,64,256,256) fp32, level=2. out = [low (2^25 floats), high (2^25)].

constexpr int IW = 256, IH = 256;

__device__ __forceinline__ float lerpf(float a, float b, float t) {
  return a + t * (b - a);
}

__global__ __launch_bounds__(256)
void haar_fused(const float* __restrict__ x,
                float* __restrict__ out_low,
                float* __restrict__ out_high) {
  const int bc = blockIdx.y;                 // channel-image 0..511
  const int ti = blockIdx.x >> 2;            // row-tile 0..7
  const int tj = blockIdx.x & 3;             // col-tile 0..3
  const int i0 = ti * 32, j0 = tj * 64;
  const int tid = threadIdx.x;
  const int lane = tid & 63;
  const int wid = tid >> 6;
  const float c512 = 1.0f / 512.0f;

  // Frames:
  //  sX   38x72: rows i0-3..i0+34, cols j0-4..j0+67 (slot = global - origin)
  //  sCH1 33x68: rows i0-1..i0+31, cols j0-1..j0+63 (65 cols used, pitch 68)
  //  sLF1 36x68: rows i0-2..i0+33, cols j0-2..j0+65
  //  sLL2/sCH2 18x34: rows i0/2-1..i0/2+16, cols j0/2-1..j0/2+32
  __shared__ float sX[38 * 72];     // 2736
  __shared__ float sCH1[33 * 68];   // 2244
  __shared__ float sLF1[36 * 68];   // 2448
  __shared__ float sLL2[18 * 34];   // 612
  __shared__ float sCH2[18 * 34];   // 612    total 8652 floats = 34,608 B

  const float* xc = x + (size_t)bc * (IH * IW);

  // ---------------- Stage 1: stage x tile, float4 path ----------------
  const int colbase = min(max(j0 - 4, 0), IW - 72);  // 0,60,124,184
  const int soff = colbase - j0 + 4;                 // +4 (tj=0), -4 (tj=3), else 0
  for (int idx = tid; idx < 38 * 18; idx += 256) {
    int r = idx / 18;
    int c4 = idx - r * 18;
    int gslot = 4 * c4 + soff;
    if ((unsigned)gslot <= 68u) {
      int gr = min(max(i0 - 3 + r, 0), IH - 1);
      const float4 v = *reinterpret_cast<const float4*>(&xc[gr * IW + colbase + 4 * c4]);
      *reinterpret_cast<float4*>(&sX[r * 72 + gslot]) = v;
    }
  }
  if (soff != 0) {                    // block-uniform
    __syncthreads();
    if (tid < 38) {
      if (soff > 0) {
        float v = sX[tid * 72 + 4];
        sX[tid * 72 + 0] = v; sX[tid * 72 + 1] = v;
        sX[tid * 72 + 2] = v; sX[tid * 72 + 3] = v;
      } else {
        float v = sX[tid * 72 + 67];
        sX[tid * 72 + 68] = v; sX[tid * 72 + 69] = v;
        sX[tid * 72 + 70] = v; sX[tid * 72 + 71] = v;
      }
    }
  }
  __syncthreads();

  // ------- Stage 2: ch1 (33x65) from sX, lane=col register row-scan -------
  {
    const int r0 = (wid < 3) ? wid * 9 : 27;
    const int r1 = (wid < 3) ? r0 + 9 : 33;
    const int xs = lane + 3;          // ch1 col lane <-> x slots lane+3, lane+4
    float a = sX[(r0 + 2) * 72 + xs], b = sX[(r0 + 2) * 72 + xs + 1];
    float s = a + b, d = a - b;
    for (int r = r0; r < r1; ++r) {
      float a2 = sX[(r + 3) * 72 + xs], b2 = sX[(r + 3) * 72 + xs + 1];
      float s2 = a2 + b2, d2 = a2 - b2;
      sCH1[r * 68 + lane] =
          0.25f * (fabsf(s - s2) + fabsf(d + d2) + fabsf(d - d2));
      s = s2; d = d2;
    }
  }
  if (tid < 33) {                     // fringe ch1 col 64 (x slots 67,68)
    int r = tid;
    float a = sX[(r + 2) * 72 + 67], b = sX[(r + 2) * 72 + 68];
    float a2 = sX[(r + 3) * 72 + 67], b2 = sX[(r + 3) * 72 + 68];
    float s = a + b, d = a - b, s2 = a2 + b2, d2 = a2 - b2;
    sCH1[r * 68 + 64] =
        0.25f * (fabsf(s - s2) + fabsf(d + d2) + fabsf(d - d2));
  }

  // ------- Stage 3: lf1 (36x68) DIRECT from sX (separable 3-tap), no sLL1 -------
  // lf1(R,C) = 0.5*((1-u)*h[R-1] + h[R] + u*h[R+1]),
  // h(row)   = 0.5*((1-t)*x[row,C-1] + x[row,C] + t*x[row,C+1])
  // t,u are the R255 closed-form weights (exact at edges via clamp).
  {
    const int l = lane;               // lf1 col slot 0..63, C = j0-2+l
    const int C = j0 - 2 + l;
    float ccf = (float)C - (float)(2 * C + 1) * c512;
    const float t = fminf(fmaxf(ccf, 0.0f), 254.0f) - (float)(C - 1);
    const int r0 = wid * 9;           // 36 rows = 4 waves x 9
    const float* rowp = &sX[r0 * 72 + l + 1];
    float xa = rowp[0], xm = rowp[1], xb = rowp[2];
    float h0 = 0.5f * ((1.0f - t) * xa + xm + t * xb);
    xa = rowp[72]; xm = rowp[73]; xb = rowp[74];
    float h1 = 0.5f * ((1.0f - t) * xa + xm + t * xb);
    for (int fr = r0; fr < r0 + 9; ++fr) {
      const float* rp = &sX[(fr + 2) * 72 + l + 1];
      xa = rp[0]; xm = rp[1]; xb = rp[2];
      float h2 = 0.5f * ((1.0f - t) * xa + xm + t * xb);
      int R = i0 - 2 + fr;
      float crf = (float)R - (float)(2 * R + 1) * c512;
      float u = fminf(fmaxf(crf, 0.0f), 254.0f) - (float)(R - 1);
      sLF1[fr * 68 + l] = 0.5f * ((1.0f - u) * h0 + h1 + u * h2);
      h0 = h1; h1 = h2;
    }
  }
  if (tid < 144) {                    // fringe lf1 cols 64..67 (36 rows x 4)
    int fr = tid >> 2, q = tid & 3;
    int l = 64 + q;
    int C = j0 - 2 + l;
    float ccf = (float)C - (float)(2 * C + 1) * c512;
    float t = fminf(fmaxf(ccf, 0.0f), 254.0f) - (float)(C - 1);
    int R = i0 - 2 + fr;
    float crf = (float)R - (float)(2 * R + 1) * c512;
    float u = fminf(fmaxf(crf, 0.0f), 254.0f) - (float)(R - 1);
    float h[3];
#pragma unroll
    for (int rr = 0; rr < 3; ++rr) {
      const float* rp = &sX[(fr + rr) * 72 + l + 1];  // max slot 70 <= 71 ok
      h[rr] = 0.5f * ((1.0f - t) * rp[0] + rp[1] + t * rp[2]);
    }
    sLF1[fr * 68 + l] = 0.5f * ((1.0f - u) * h[0] + h[1] + u * h[2]);
  }
  __syncthreads();

  // ------- Stage 4: stride-2 Haar on lf1 -> ll2/ch2 (18x34), float2 reads -------
  for (int idx = tid; idx < 18 * 32; idx += 256) {
    int pr = idx >> 5, pc = idx & 31;
    const float2 f0 = *reinterpret_cast<const float2*>(&sLF1[(2 * pr) * 68 + 2 * pc]);
    const float2 f1 = *reinterpret_cast<const float2*>(&sLF1[(2 * pr + 1) * 68 + 2 * pc]);
    float sa = f0.x + f0.y, sb = f1.x + f1.y;
    float da = f0.x - f0.y, db = f1.x - f1.y;
    sLL2[pr * 34 + pc] = 0.25f * (sa + sb);
    sCH2[pr * 34 + pc] =
        0.25f * (fabsf(sa - sb) + fabsf(da + db) + fabsf(da - db));
  }
  if (tid < 36) {                     // fringe cols 32,33
    int pr = tid >> 1, pc = 32 + (tid & 1);
    const float2 f0 = *reinterpret_cast<const float2*>(&sLF1[(2 * pr) * 68 + 2 * pc]);
    const float2 f1 = *reinterpret_cast<const float2*>(&sLF1[(2 * pr + 1) * 68 + 2 * pc]);
    float sa = f0.x + f0.y, sb = f1.x + f1.y;
    float da = f0.x - f0.y, db = f1.x - f1.y;
    sLL2[pr * 34 + pc] = 0.25f * (sa + sb);
    sCH2[pr * 34 + pc] =
        0.25f * (fabsf(sa - sb) + fabsf(da + db) + fabsf(da - db));
  }
  __syncthreads();

  // ------- Stage 5: outputs, 4 consecutive cols/thread, float4 stores -------
  {
    const int cg = tid & 15, rb = tid >> 4;
    const int cbase = 4 * cg;
    float fc1[4], fc2[4];
#pragma unroll
    for (int m = 0; m < 4; ++m) {
      int jj = j0 + cbase + m;
      float ccf = (float)jj - (float)(2 * jj + 1) * c512;
      fc1[m] = fminf(fmaxf(ccf, 0.0f), 254.0f) - (float)(jj - 1);
      int qu = (jj - 1) >> 1;
      fc2[m] = fminf(fmaxf(0.5f * (float)jj - 0.25f, 0.0f), 127.0f) - (float)qu;
    }
    const int qs0 = (cbase + 1) >> 1;   // ll2/ch2 col slot for m=0
    const size_t obase = (size_t)bc * (IH * IW);

#pragma unroll
    for (int k = 0; k < 2; ++k) {
      int r = rb + 16 * k;              // 0..31
      int i = i0 + r;
      float crf = (float)i - (float)(2 * i + 1) * c512;
      float fr1 = fminf(fmaxf(crf, 0.0f), 254.0f) - (float)(i - 1);
      int pu = (i - 1) >> 1;
      float fr2 = fminf(fmaxf(0.5f * (float)i - 0.25f, 0.0f), 127.0f) - (float)pu;
      int ps = (r + 1) >> 1;            // ll2/ch2 row slot

      const float* chA = &sCH1[r * 68 + cbase];
      const float* chB = chA + 68;
      const float* llA = &sLL2[ps * 34 + qs0];
      const float* llB = llA + 34;
      const float* c2A = &sCH2[ps * 34 + qs0];
      const float* c2B = c2A + 34;

      float av[5], bv[5];
#pragma unroll
      for (int m = 0; m < 5; ++m) { av[m] = chA[m]; bv[m] = chB[m]; }
      float lav[4], lbv[4], gav[4], gbv[4];
#pragma unroll
      for (int m = 0; m < 4; ++m) {
        lav[m] = llA[m]; lbv[m] = llB[m];
        gav[m] = c2A[m]; gbv[m] = c2B[m];
      }

      float lo[4], hi[4];
#pragma unroll
      for (int m = 0; m < 4; ++m) {
        const int k2 = (m == 0) ? 0 : (m == 3 ? 2 : 1);  // col-slot pattern {0,1,1,2}
        float h1 = lerpf(lerpf(av[m], av[m + 1], fc1[m]),
                         lerpf(bv[m], bv[m + 1], fc1[m]), fr1);
        float l_ = lerpf(lerpf(lav[k2], lav[k2 + 1], fc2[m]),
                         lerpf(lbv[k2], lbv[k2 + 1], fc2[m]), fr2);
        float h2 = lerpf(lerpf(gav[k2], gav[k2 + 1], fc2[m]),
                         lerpf(gbv[k2], gbv[k2 + 1], fc2[m]), fr2);
        lo[m] = l_;
        hi[m] = 0.5f * (h1 + h2);
      }
      float4 lowv = make_float4(lo[0], lo[1], lo[2], lo[3]);
      float4 highv = make_float4(hi[0], hi[1], hi[2], hi[3]);
      size_t off = obase + (size_t)i * IW + (j0 + cbase);
      *reinterpret_cast<float4*>(&out_low[off]) = lowv;
      *reinterpret_cast<float4*>(&out_high[off]) = highv;
    }
  }
}

extern "C" void kernel_launch(void* const* d_in, const int* in_sizes, int n_in,
                              void* d_out, int out_size, void* d_ws, size_t ws_size,
                              hipStream_t stream) {
  (void)in_sizes; (void)n_in; (void)d_ws; (void)ws_size; (void)out_size;
  const float* x = (const float*)d_in[0];
  float* out_low = (float*)d_out;
  float* out_high = out_low + (size_t)8 * 64 * 256 * 256;

  dim3 grid(32, 512, 1);   // 32 tiles (8 row x 4 col) x 512 channel-images
  dim3 block(256, 1, 1);
  haar_fused<<<grid, block, 0, stream>>>(x, out_low, out_high);
}